// Round 1
// baseline (3480.728 us; speedup 1.0000x reference)
//
#include <hip/hip_runtime.h>
#include <hip/hip_bf16.h>

// Encoder: e = embed[x]; q = LSTM_q(e); k = LSTM_k(e); A = q @ k^T (per batch)
// B=32, T=512, D=512, NUM_TOKENS=14.
//
// Key algorithmic move: only 14 distinct tokens -> input projection
// pre[b,t,:] = embed[x[b,t]] @ W_ih^T + b_ih + b_hh is a 14-row table.
// Recurrence h @ W_hh^T done with bf16 MFMA (f32 accumulate); c/h/pre/A in f32.
//
// ws layout (floats):
//   q      [32][512][512]            8388608 f
//   k      [32][512][512]            8388608 f
//   c      [2][32][512]                32768 f
//   pre    [2][14][2048]               57344 f
//   Wbf    [2][2048][512] ushort    (4 MB)
//   hbf    [2 phase][2 l][32][512] ushort (128 KB)
// total ~68.5 MiB

#define TB 32
#define TT 512
#define TD 512
#define NTOK 14

typedef __attribute__((ext_vector_type(8))) short short8;
typedef __attribute__((ext_vector_type(4))) float f32x4;

__device__ __forceinline__ float fsigmoid(float v) { return 1.f / (1.f + __expf(-v)); }
__device__ __forceinline__ float ftanh(float v) {
    float a = fabsf(v);
    float e = __expf(-2.f * a);
    float r = (1.f - e) / (1.f + e);
    return copysignf(r, v);
}
__device__ __forceinline__ unsigned short f2bf(float f) {
    __hip_bfloat16 h = __float2bfloat16(f);
    return __builtin_bit_cast(unsigned short, h);
}

// ---- pre_tab[l][tok][2048] = embed[tok] @ W_ih_l^T + b_ih_l + b_hh_l ----
__global__ __launch_bounds__(256) void pre_tab_kernel(
    const float* __restrict__ embed,
    const float* __restrict__ Wih_q, const float* __restrict__ bih_q, const float* __restrict__ bhh_q,
    const float* __restrict__ Wih_k, const float* __restrict__ bih_k, const float* __restrict__ bhh_k,
    float* __restrict__ pre)
{
    int idx = blockIdx.x * 256 + threadIdx.x;   // 2*14*2048 = 57344 exactly
    int l = idx / (NTOK * 4 * TD);
    int r = idx % (NTOK * 4 * TD);
    int tok = r / (4 * TD), j = r % (4 * TD);
    const float* Wih = l ? Wih_k : Wih_q;
    float acc = l ? (bih_k[j] + bhh_k[j]) : (bih_q[j] + bhh_q[j]);
    const float4* e4 = (const float4*)(embed + (size_t)tok * TD);
    const float4* w4 = (const float4*)(Wih + (size_t)j * TD);
    for (int t2 = 0; t2 < TD / 4; ++t2) {
        float4 e = e4[t2], w = w4[t2];
        acc += e.x * w.x + e.y * w.y + e.z * w.z + e.w * w.w;
    }
    pre[idx] = acc;
}

// ---- W_hh (both LSTMs) f32 -> bf16 bits ----
__global__ __launch_bounds__(256) void wconv_kernel(
    const float* __restrict__ Whh_q, const float* __restrict__ Whh_k,
    unsigned short* __restrict__ Wbf)
{
    int idx = blockIdx.x * 256 + threadIdx.x;   // float4 units: 2*2048*512/4 = 524288
    const int half = (4 * TD * TD) / 4;         // 262144
    const float* src = (idx < half) ? Whh_q : Whh_k;
    int i = (idx < half) ? idx : idx - half;
    float4 v = ((const float4*)src)[i];
    ushort4 o;
    o.x = f2bf(v.x); o.y = f2bf(v.y); o.z = f2bf(v.z); o.w = f2bf(v.w);
    ((ushort4*)Wbf)[idx] = o;
}

// ---- one LSTM timestep for BOTH lstms ----
// grid 128: wg>>6 = lstm l, (wg&63)*8 = dim chunk d0 (8 dims/WG).
// WG computes gates[32 b][4 gates x 8 dims] = h(t-1) @ Wslice^T via MFMA 16x16x32 bf16,
// adds pre_tab row per token, updates c/h, writes h (f32 into q/k history, bf16 into hbf).
// hbf double-buffered on t parity (read t-1 buffer, write t buffer) -> no cross-WG race.
__global__ __launch_bounds__(256) void lstm_step(
    int t,
    const unsigned short* __restrict__ Wbf,
    const float* __restrict__ pre,
    const int* __restrict__ x,
    float* __restrict__ qout, float* __restrict__ kout,
    unsigned short* __restrict__ hbf,
    float* __restrict__ c_ws)
{
    __shared__ float g_lds[32][33];   // [row 0..31 = gate*8+dd][batch], +1 pad
    int wg = blockIdx.x;
    int l = wg >> 6;
    int d0 = (wg & 63) << 3;
    int tid = threadIdx.x;
    int lane = tid & 63;
    int wv = tid >> 6;     // 4 waves
    int mt = wv & 1;       // batch tile: b = mt*16 ..
    int nt = wv >> 1;      // row tile: rows nt*16 .. of this WG's 32 rows

    f32x4 acc = {0.f, 0.f, 0.f, 0.f};
    if (t > 0) {
        // A-frag: h[b][k]  lane: b = mt*16 + (lane&15), k = (lane>>4)*8 + j
        const unsigned short* hrow = hbf
            + (size_t)((((t - 1) & 1) * 2 + l) * TB + (mt * 16 + (lane & 15))) * TD
            + ((lane >> 4) * 8);
        // B-frag: B[k][n] = W[row rr][k]  lane: rr = nt*16 + (lane&15)
        int rr = nt * 16 + (lane & 15);
        const unsigned short* wrow = Wbf + (size_t)l * (4 * TD * TD)
            + (size_t)((rr >> 3) * TD + d0 + (rr & 7)) * TD
            + ((lane >> 4) * 8);
#pragma unroll
        for (int kk = 0; kk < 16; ++kk) {
            short8 a = *(const short8*)(hrow + kk * 32);
            short8 b = *(const short8*)(wrow + kk * 32);
            acc = __builtin_amdgcn_mfma_f32_16x16x32_bf16(a, b, acc, 0, 0, 0);
        }
    }
    // C/D layout: n(col)=lane&15 -> gate-row, m(row)=(lane>>4)*4+reg -> batch
    {
        int gr = nt * 16 + (lane & 15);
        int gb = mt * 16 + ((lane >> 4) << 2);
#pragma unroll
        for (int r2 = 0; r2 < 4; ++r2) g_lds[gr][gb + r2] = acc[r2];
    }
    __syncthreads();

    // state update: thread <-> (b, dd)
    int b = tid >> 3, dd = tid & 7;
    int tok = x[b * TT + t];
    const float* pr = pre + ((size_t)l * NTOK + tok) * (4 * TD) + d0 + dd;
    float gi = g_lds[dd][b]      + pr[0 * TD];
    float gf = g_lds[8 + dd][b]  + pr[1 * TD];
    float gg = g_lds[16 + dd][b] + pr[2 * TD];
    float go = g_lds[24 + dd][b] + pr[3 * TD];
    float i_ = fsigmoid(gi), f_ = fsigmoid(gf), g_ = ftanh(gg), o_ = fsigmoid(go);
    float* cp = c_ws + ((size_t)l * TB + b) * TD + d0 + dd;
    float cold = (t > 0) ? *cp : 0.f;
    float cn = f_ * cold + i_ * g_;
    *cp = cn;
    float h = o_ * ftanh(cn);
    float* out = l ? kout : qout;
    out[((size_t)b * TT + t) * TD + d0 + dd] = h;
    hbf[(size_t)(((t & 1) * 2 + l) * TB + b) * TD + d0 + dd] = f2bf(h);
}

// ---- A[b] = q[b] @ k[b]^T, f32, 64x64 tile / WG, 4x4 per thread ----
__global__ __launch_bounds__(256) void qk_gemm(
    const float* __restrict__ q, const float* __restrict__ k, float* __restrict__ A)
{
    __shared__ float qs[64][68];
    __shared__ float ks[64][68];
    int b = blockIdx.y;
    int t0 = (blockIdx.x >> 3) * 64;
    int s0 = (blockIdx.x & 7) * 64;
    const float* qb = q + (size_t)b * TT * TD;
    const float* kb = k + (size_t)b * TT * TD;
    int tid = threadIdx.x;
    int ty = tid >> 4, tx = tid & 15;
    float accr[4][4] = {};
    for (int k0 = 0; k0 < TD; k0 += 64) {
        for (int i = tid; i < 64 * 16; i += 256) {
            int r = i >> 4, c4 = i & 15;
            ((float4*)&qs[r][0])[c4] = ((const float4*)(qb + (size_t)(t0 + r) * TD + k0))[c4];
            ((float4*)&ks[r][0])[c4] = ((const float4*)(kb + (size_t)(s0 + r) * TD + k0))[c4];
        }
        __syncthreads();
#pragma unroll 4
        for (int kk = 0; kk < 64; kk += 4) {
            float4 qv[4], kv[4];
#pragma unroll
            for (int i = 0; i < 4; ++i) qv[i] = *(const float4*)&qs[ty * 4 + i][kk];
#pragma unroll
            for (int j = 0; j < 4; ++j) kv[j] = *(const float4*)&ks[tx * 4 + j][kk];
#pragma unroll
            for (int i = 0; i < 4; ++i)
#pragma unroll
                for (int j = 0; j < 4; ++j)
                    accr[i][j] += qv[i].x * kv[j].x + qv[i].y * kv[j].y
                                + qv[i].z * kv[j].z + qv[i].w * kv[j].w;
        }
        __syncthreads();
    }
    for (int i = 0; i < 4; ++i)
        for (int j = 0; j < 4; ++j)
            A[(size_t)b * TT * TT + (size_t)(t0 + ty * 4 + i) * TT + (s0 + tx * 4 + j)] = accr[i][j];
}

extern "C" void kernel_launch(void* const* d_in, const int* in_sizes, int n_in,
                              void* d_out, int out_size, void* d_ws, size_t ws_size,
                              hipStream_t stream)
{
    const int*   x      = (const int*)d_in[0];
    const float* embed  = (const float*)d_in[1];
    const float* Wih_q  = (const float*)d_in[2];
    const float* Whh_q  = (const float*)d_in[3];
    const float* bih_q  = (const float*)d_in[4];
    const float* bhh_q  = (const float*)d_in[5];
    const float* Wih_k  = (const float*)d_in[6];
    const float* Whh_k  = (const float*)d_in[7];
    const float* bih_k  = (const float*)d_in[8];
    const float* bhh_k  = (const float*)d_in[9];

    float* ws   = (float*)d_ws;
    float* q    = ws;                                   // 8388608 f
    float* kbuf = q + (size_t)TB * TT * TD;             // 8388608 f
    float* c_ws = kbuf + (size_t)TB * TT * TD;          // 32768 f
    float* pre  = c_ws + 2 * TB * TD;                   // 57344 f
    unsigned short* Wbf = (unsigned short*)(pre + 2 * NTOK * 4 * TD);  // 2097152 us
    unsigned short* hbf = Wbf + (size_t)2 * 4 * TD * TD;               // 65536 us

    pre_tab_kernel<<<224, 256, 0, stream>>>(embed, Wih_q, bih_q, bhh_q,
                                            Wih_k, bih_k, bhh_k, pre);
    wconv_kernel<<<2048, 256, 0, stream>>>(Whh_q, Whh_k, Wbf);
    for (int t = 0; t < TT; ++t)
        lstm_step<<<128, 256, 0, stream>>>(t, Wbf, pre, x, q, kbuf, hbf, c_ws);
    dim3 g(64, 32);
    qk_gemm<<<g, 256, 0, stream>>>(q, kbuf, (float*)d_out);
}